// Round 8
// baseline (261.978 us; speedup 1.0000x reference)
//
#include <hip/hip_runtime.h>

// Problem constants: B=32, S=128, H=512, K=8
#define BB 32
#define SS 128
#define HH 512
#define KC 8
#define NN 4096  // KC*HH

typedef __attribute__((ext_vector_type(8))) short bf16x8;
typedef __attribute__((ext_vector_type(4))) float f32x4;

__device__ __forceinline__ unsigned short f2bf(float f) {
  unsigned int u = __float_as_uint(f);
  u += 0x7fffu + ((u >> 16) & 1u);   // round-to-nearest-even
  return (unsigned short)(u >> 16);
}
__device__ __forceinline__ float bf2f(unsigned short h) {
  return __uint_as_float(((unsigned int)h) << 16);
}
__device__ __forceinline__ float tanh_fast(float x) {
  float e = __expf(2.0f * x);
  return 1.0f - 2.0f / (e + 1.0f);
}
__device__ __forceinline__ void async16(const void* g, void* lds) {
  __builtin_amdgcn_global_load_lds(
      (const __attribute__((address_space(1))) unsigned int*)g,
      (__attribute__((address_space(3))) unsigned int*)lds, 16, 0, 0);
}

// ---- conversion kernels ---------------------------------------------------
// A/P: fp32 [B,S,H] -> hi/lo row-major AND hi-only transposed [B,H,S], one read.
__global__ __launch_bounds__(256) void convert_ap(
    const float* __restrict__ Xa, const float* __restrict__ Xb,
    unsigned short* __restrict__ hia, unsigned short* __restrict__ loa,
    unsigned short* __restrict__ hiTa,
    unsigned short* __restrict__ hib, unsigned short* __restrict__ lob,
    unsigned short* __restrict__ hiTb) {
  const float* X = blockIdx.z ? Xb : Xa;
  unsigned short* hi = blockIdx.z ? hib : hia;
  unsigned short* lo = blockIdx.z ? lob : loa;
  unsigned short* hiT = blockIdx.z ? hiTb : hiTa;
  __shared__ float t[32][33];
  const int h0 = blockIdx.x * 32;
  const int s0 = (blockIdx.y & 3) * 32;
  const size_t b = blockIdx.y >> 2;
  const int tx = threadIdx.x & 31, ty = threadIdx.x >> 5;
#pragma unroll
  for (int r = 0; r < 4; ++r) {
    float f = X[b * (SS * HH) + (size_t)(s0 + ty + r * 8) * HH + h0 + tx];
    t[ty + r * 8][tx] = f;
    size_t o = b * (SS * HH) + (size_t)(s0 + ty + r * 8) * HH + h0 + tx;
    unsigned short h = f2bf(f);
    hi[o] = h;
    lo[o] = f2bf(f - bf2f(h));
  }
  __syncthreads();
#pragma unroll
  for (int r = 0; r < 4; ++r) {
    float f = t[tx][ty + r * 8];
    size_t o = b * (SS * HH) + (size_t)(h0 + ty + r * 8) * SS + s0 + tx;
    hiT[o] = f2bf(f);
  }
}

// G [512, 4096] fp32 -> G^T [4096, 512] (hi, lo) bf16; z selects G1/G2.
__global__ __launch_bounds__(256) void convert_transpose_g(
    const float* __restrict__ Ga, const float* __restrict__ Gb,
    unsigned short* __restrict__ ha, unsigned short* __restrict__ la,
    unsigned short* __restrict__ hb, unsigned short* __restrict__ lb) {
  const float* G = blockIdx.z ? Gb : Ga;
  unsigned short* hiT = blockIdx.z ? hb : ha;
  unsigned short* loT = blockIdx.z ? lb : la;
  __shared__ float t[32][33];
  const int bx = blockIdx.x * 32;  // n
  const int by = blockIdx.y * 32;  // k
  const int tx = threadIdx.x & 31, ty = threadIdx.x >> 5;
#pragma unroll
  for (int r = 0; r < 4; ++r)
    t[ty + r * 8][tx] = G[(size_t)(by + ty + r * 8) * NN + bx + tx];
  __syncthreads();
#pragma unroll
  for (int r = 0; r < 4; ++r) {
    float f = t[tx][ty + r * 8];
    size_t o = (size_t)(bx + ty + r * 8) * HH + by + tx;
    unsigned short h = f2bf(f);
    hiT[o] = h;
    loT[o] = f2bf(f - bf2f(h));
  }
}

// ---- fused proj+score: block (k, b, br) -----------------------------------
// Phase A (per g-chunk gc of 128): proj subtile [128 s x 128 g] for fixed k:
//   C = A[128,512] x G^T[n0..n0+128, 512], n0 = k*512 + gc*128 (m97-shape core).
// Phase B (per 32-g slice): proj frags -> LDS bf16 hi/lo; R[128 t x 32 g]
//   hi/lo staged via global_load_lds; raw[s,t] += proj . R (3-product split).
// Epilogue: atomicAdd scoreBuf[br,b,s,t] += v[k]*tanh(raw).
// LDS byte map, phase A: Ahi[0,8K) Alo[8K,16K) Bhi[16K,24K) Blo[24K,32K).
//          phase B: Pslice hi[0,8K) lo[8K,16K); Rslice hi[16K,24K) lo[24K,32K).
__global__ __launch_bounds__(256, 2) void fused_score(
    const unsigned short* __restrict__ Ahi, const unsigned short* __restrict__ Alo,
    const unsigned short* __restrict__ Phi, const unsigned short* __restrict__ Plo,
    const unsigned short* __restrict__ G1h, const unsigned short* __restrict__ G1l,
    const unsigned short* __restrict__ G2h, const unsigned short* __restrict__ G2l,
    const float* __restrict__ v1, const float* __restrict__ v2,
    float* __restrict__ scoreBuf, int bc) {
  __shared__ char smem[32768];
  unsigned short* sm = (unsigned short*)smem;
  const int k = blockIdx.x;   // 0..7 — fast dim: same-(k,br) blocks share an XCD (G reuse)
  const int b = blockIdx.y;
  const int brx = blockIdx.z;
  const int tid = threadIdx.x, w = tid >> 6, L = tid & 63;
  const int wm = w >> 1, wn = w & 1;
  const int q = L >> 4, c = L & 15;

  // Left operand: aspect A for BOTH branches (faithful to source).
  const unsigned short* Ah = Ahi + (size_t)b * SS * HH;
  const unsigned short* Al = Alo + (size_t)b * SS * HH;
  const unsigned short* Gh = brx ? G2h : G1h;
  const unsigned short* Gl = brx ? G2l : G1l;
  // Right matrix: branch0 -> polarity, branch1 -> aspect.
  const unsigned short* Rh = (brx ? Ahi : Phi) + (size_t)b * SS * HH;
  const unsigned short* Rl = (brx ? Alo : Plo) + (size_t)b * SS * HH;

  const int srow = w * 32 + (L >> 2);
  const int scol = (L & 3) * 8;
  const unsigned short* pAh = Ah + (size_t)srow * HH + scol;
  const unsigned short* pAl = Al + (size_t)srow * HH + scol;
  const unsigned short* pRh = Rh + (size_t)srow * HH + scol;
  const unsigned short* pRl = Rl + (size_t)srow * HH + scol;
  const unsigned lbase = (unsigned)w * 2048;
  const int ar = (wm * 64 + (L & 15)) * 32 + (L >> 4) * 8;
  const int br_ = (wn * 64 + (L & 15)) * 32 + (L >> 4) * 8;

  f32x4 raw[4][4];
#pragma unroll
  for (int i = 0; i < 4; ++i)
#pragma unroll
    for (int j = 0; j < 4; ++j) raw[i][j] = (f32x4)(0.0f);

  for (int gc = 0; gc < 4; ++gc) {
    // ---------- phase A: proj subtile ----------
    const size_t n0 = (size_t)k * 512 + (size_t)gc * 128;
    const unsigned short* pBh = Gh + (n0 + srow) * HH + scol;
    const unsigned short* pBl = Gl + (n0 + srow) * HH + scol;
    f32x4 acc[4][4];
#pragma unroll
    for (int i = 0; i < 4; ++i)
#pragma unroll
      for (int j = 0; j < 4; ++j) acc[i][j] = (f32x4)(0.0f);

    for (int kt = 0; kt < 16; ++kt) {
      const int k0 = kt * 32;
      async16(pAh + k0, smem + lbase);
      async16(pAh + k0 + 16 * HH, smem + lbase + 1024);
      async16(pAl + k0, smem + 8192 + lbase);
      async16(pAl + k0 + 16 * HH, smem + 8192 + lbase + 1024);
      async16(pBh + k0, smem + 16384 + lbase);
      async16(pBh + k0 + 16 * HH, smem + 16384 + lbase + 1024);
      async16(pBl + k0, smem + 24576 + lbase);
      async16(pBl + k0 + 16 * HH, smem + 24576 + lbase + 1024);
      __syncthreads();
      bf16x8 ah[4], al[4], bh[4], bl[4];
#pragma unroll
      for (int i = 0; i < 4; ++i) {
        ah[i] = *(const bf16x8*)&sm[ar + i * 512];
        al[i] = *(const bf16x8*)&sm[4096 + ar + i * 512];
        bh[i] = *(const bf16x8*)&sm[8192 + br_ + i * 512];
        bl[i] = *(const bf16x8*)&sm[12288 + br_ + i * 512];
      }
#pragma unroll
      for (int i = 0; i < 4; ++i)
#pragma unroll
        for (int j = 0; j < 4; ++j) {
          acc[i][j] = __builtin_amdgcn_mfma_f32_16x16x32_bf16(ah[i], bh[j], acc[i][j], 0, 0, 0);
          acc[i][j] = __builtin_amdgcn_mfma_f32_16x16x32_bf16(ah[i], bl[j], acc[i][j], 0, 0, 0);
          acc[i][j] = __builtin_amdgcn_mfma_f32_16x16x32_bf16(al[i], bh[j], acc[i][j], 0, 0, 0);
        }
      __syncthreads();
    }

    // ---------- phase B: raw += projTile @ R, in 32-g slices ----------
#pragma unroll
    for (int sl = 0; sl < 4; ++sl) {
      // R slice staging first (DMA overlaps the ds_writes below)
      const int gg = gc * 128 + sl * 32;
      async16(pRh + gg, smem + 16384 + lbase);
      async16(pRh + gg + 16 * HH, smem + 16384 + lbase + 1024);
      async16(pRl + gg, smem + 24576 + lbase);
      async16(pRl + gg + 16 * HH, smem + 24576 + lbase + 1024);
      // proj slice -> LDS bf16 hi/lo [128 s][32 g]; held by waves with wn==sl>>1
      if (wn == (sl >> 1)) {
        const int jj0 = (sl & 1) * 2;
#pragma unroll
        for (int i = 0; i < 4; ++i)
#pragma unroll
          for (int jd = 0; jd < 2; ++jd) {
            f32x4 vfr = acc[i][jj0 + jd];
            const int gl = jd * 16 + c;
#pragma unroll
            for (int r = 0; r < 4; ++r) {
              const int row = wm * 64 + i * 16 + q * 4 + r;
              float f = vfr[r];
              unsigned short h = f2bf(f);
              sm[row * 32 + gl] = h;
              sm[4096 + row * 32 + gl] = f2bf(f - bf2f(h));
            }
          }
      }
      __syncthreads();
      bf16x8 sa_h[4], sa_l[4], sb_h[4], sb_l[4];
#pragma unroll
      for (int i = 0; i < 4; ++i) {
        const int ao = (wm * 64 + i * 16 + (L & 15)) * 32 + (L >> 4) * 8;
        sa_h[i] = *(const bf16x8*)&sm[ao];
        sa_l[i] = *(const bf16x8*)&sm[4096 + ao];
      }
#pragma unroll
      for (int j = 0; j < 4; ++j) {
        const int bo = (wn * 64 + j * 16 + (L & 15)) * 32 + (L >> 4) * 8;
        sb_h[j] = *(const bf16x8*)&sm[8192 + bo];
        sb_l[j] = *(const bf16x8*)&sm[12288 + bo];
      }
#pragma unroll
      for (int i = 0; i < 4; ++i)
#pragma unroll
        for (int j = 0; j < 4; ++j) {
          raw[i][j] = __builtin_amdgcn_mfma_f32_16x16x32_bf16(sa_h[i], sb_h[j], raw[i][j], 0, 0, 0);
          raw[i][j] = __builtin_amdgcn_mfma_f32_16x16x32_bf16(sa_h[i], sb_l[j], raw[i][j], 0, 0, 0);
          raw[i][j] = __builtin_amdgcn_mfma_f32_16x16x32_bf16(sa_l[i], sb_h[j], raw[i][j], 0, 0, 0);
        }
      __syncthreads();
    }
  }

  // ---------- epilogue: score contribution via atomics ----------
  const float vk = (brx ? v2 : v1)[k];
  float* dst = scoreBuf + ((size_t)brx * bc + b) * (SS * SS);
#pragma unroll
  for (int i = 0; i < 4; ++i)
#pragma unroll
    for (int j = 0; j < 4; ++j) {
      const int row0 = wm * 64 + i * 16 + q * 4;
      const int col = wn * 64 + j * 16 + c;
#pragma unroll
      for (int r = 0; r < 4; ++r)
        atomicAdd(&dst[(size_t)(row0 + r) * SS + col], vk * tanh_fast(raw[i][j][r]));
    }
}

// ---- softmax over t -> attn weights bf16-hi -------------------------------
// grid (groups = bc*2, 8 rt); block = 16 s-rows x 128 t.
__global__ __launch_bounds__(256) void softmax_attn(
    const float* __restrict__ scoreBuf, unsigned short* __restrict__ attnW) {
  const int x = blockIdx.x, rt = blockIdx.y;
  const int tid = threadIdx.x, tx = tid & 15, ty = tid >> 4;
  const float* src = scoreBuf + (size_t)x * (SS * SS) + (size_t)(rt * 16 + ty) * SS + tx * 8;
  float sc[8];
  *(float4*)&sc[0] = *(const float4*)&src[0];
  *(float4*)&sc[4] = *(const float4*)&src[4];
  float mx = sc[0];
#pragma unroll
  for (int j = 1; j < 8; ++j) mx = fmaxf(mx, sc[j]);
#pragma unroll
  for (int off = 1; off < 16; off <<= 1) mx = fmaxf(mx, __shfl_xor(mx, off, 16));
  float p[8], ssum = 0.0f;
#pragma unroll
  for (int j = 0; j < 8; ++j) { p[j] = __expf(sc[j] - mx); ssum += p[j]; }
#pragma unroll
  for (int off = 1; off < 16; off <<= 1) ssum += __shfl_xor(ssum, off, 16);
  float inv = 1.0f / ssum;
  ushort4 h0, h1;
  h0.x = f2bf(p[0] * inv); h0.y = f2bf(p[1] * inv);
  h0.z = f2bf(p[2] * inv); h0.w = f2bf(p[3] * inv);
  h1.x = f2bf(p[4] * inv); h1.y = f2bf(p[5] * inv);
  h1.z = f2bf(p[6] * inv); h1.w = f2bf(p[7] * inv);
  size_t abase = (size_t)x * (SS * SS) + (size_t)(rt * 16 + ty) * SS + tx * 8;
  *(ushort4*)&attnW[abase] = h0;
  *(ushort4*)&attnW[abase + 4] = h1;
}

// ---- PV + residual: out[64 s x 128 h] = base + attn[64x128] @ V[128x128] --
__global__ __launch_bounds__(256) void pv_res2(
    const unsigned short* __restrict__ attnW,
    const unsigned short* __restrict__ PTh, const unsigned short* __restrict__ ATh,
    const float* __restrict__ Abase, const float* __restrict__ Pbase,
    float* __restrict__ out1, float* __restrict__ out2, int bc) {
  __shared__ char smem[12288];  // A [64][32] 4 KB | B [128][32] 8 KB
  unsigned short* sm = (unsigned short*)smem;
  const int x = blockIdx.x;
  const int brx = (x >= bc) ? 1 : 0;
  const int b = x - (brx ? bc : 0);
  const int hc = blockIdx.y & 3, sh = blockIdx.y >> 2;
  const int tid = threadIdx.x, w = tid >> 6, L = tid & 63;
  const int wm = w >> 1, wn = w & 1;

  const unsigned short* Aw = attnW + (size_t)x * (SS * SS) + (size_t)(sh * 64) * SS;
  const unsigned short* Vh = (brx ? ATh : PTh) + (size_t)b * HH * SS + (size_t)(hc * 128) * SS;
  const float* base = (brx ? Pbase : Abase) + (size_t)b * SS * HH;
  float* outp = (brx ? out2 : out1) + (size_t)b * SS * HH;

  f32x4 acc[2][4];
#pragma unroll
  for (int i = 0; i < 2; ++i)
#pragma unroll
    for (int j = 0; j < 4; ++j) acc[i][j] = (f32x4)(0.0f);

  const int arow = w * 16 + (L >> 2);
  const int brow = w * 32 + (L >> 2);
  const int scol = (L & 3) * 8;
  const int afr = (wm * 32 + (L & 15)) * 32 + (L >> 4) * 8;
  const int bfr = 2048 + (wn * 64 + (L & 15)) * 32 + (L >> 4) * 8;

  for (int kt = 0; kt < 4; ++kt) {
    const int k0 = kt * 32;
    async16(Aw + (size_t)arow * SS + k0 + scol, smem + w * 1024);
    async16(Vh + (size_t)brow * SS + k0 + scol, smem + 4096 + w * 2048);
    async16(Vh + (size_t)(brow + 16) * SS + k0 + scol, smem + 4096 + w * 2048 + 1024);
    __syncthreads();
    bf16x8 af[2], bf[4];
#pragma unroll
    for (int i = 0; i < 2; ++i) af[i] = *(const bf16x8*)&sm[afr + i * 512];
#pragma unroll
    for (int j = 0; j < 4; ++j) bf[j] = *(const bf16x8*)&sm[bfr + j * 512];
#pragma unroll
    for (int i = 0; i < 2; ++i)
#pragma unroll
      for (int j = 0; j < 4; ++j)
        acc[i][j] = __builtin_amdgcn_mfma_f32_16x16x32_bf16(af[i], bf[j], acc[i][j], 0, 0, 0);
    __syncthreads();
  }

  const int q = L >> 4, c = L & 15;
#pragma unroll
  for (int i = 0; i < 2; ++i)
#pragma unroll
    for (int j = 0; j < 4; ++j) {
      const int srow = sh * 64 + wm * 32 + i * 16 + q * 4;
      const int hcol = hc * 128 + wn * 64 + j * 16 + c;
#pragma unroll
      for (int r = 0; r < 4; ++r) {
        size_t o = (size_t)(srow + r) * HH + hcol;
        outp[o] = base[o] + acc[i][j][r];
      }
    }
}

extern "C" void kernel_launch(void* const* d_in, const int* in_sizes, int n_in,
                              void* d_out, int out_size, void* d_ws, size_t ws_size,
                              hipStream_t stream) {
  const float* A  = (const float*)d_in[0];
  const float* P  = (const float*)d_in[1];
  const float* G1 = (const float*)d_in[2];
  const float* G2 = (const float*)d_in[3];
  const float* v1 = (const float*)d_in[4];
  const float* v2 = (const float*)d_in[5];
  float* out1 = (float*)d_out;
  float* out2 = out1 + (size_t)BB * SS * HH;

  const size_t NA = (size_t)BB * SS * HH;  // 2M
  const size_t NG = (size_t)HH * KC * HH;  // 2M
  unsigned short* Ahi = (unsigned short*)d_ws;
  unsigned short* Alo = Ahi + NA;
  unsigned short* Phi = Alo + NA;
  unsigned short* Plo = Phi + NA;
  unsigned short* G1h = Plo + NA;
  unsigned short* G1l = G1h + NG;
  unsigned short* G2h = G1l + NG;
  unsigned short* G2l = G2h + NG;
  unsigned short* ATh = G2l + NG;
  unsigned short* PTh = ATh + NA;

  const size_t fixedBytes = (6 * NA + 4 * NG) * sizeof(unsigned short);  // 40 MB
  // per batch: scoreBuf 2*16K fp32 (128 KB) + attnW 2*16K bf16 (64 KB)
  const size_t perB = 2 * (size_t)SS * SS * (sizeof(float) + sizeof(unsigned short));
  size_t rem = ws_size > fixedBytes ? ws_size - fixedBytes : 0;
  int Bc = (int)(rem / perB);
  if (Bc < 1) Bc = 1;
  if (Bc > BB) Bc = BB;
  float* scoreBuf = (float*)((char*)d_ws + fixedBytes);
  unsigned short* attnW = (unsigned short*)(scoreBuf + 2 * (size_t)Bc * SS * SS);

  convert_ap<<<dim3(HH / 32, (SS / 32) * BB, 2), 256, 0, stream>>>(
      A, P, Ahi, Alo, ATh, Phi, Plo, PTh);
  convert_transpose_g<<<dim3(NN / 32, HH / 32, 2), 256, 0, stream>>>(
      G1, G2, G1h, G1l, G2h, G2l);

  for (int b0 = 0; b0 < BB; b0 += Bc) {
    int bc = (Bc < BB - b0) ? Bc : (BB - b0);
    size_t off = (size_t)b0 * SS * HH;  // element offset (both layouts)
    hipMemsetAsync(scoreBuf, 0, 2 * (size_t)bc * SS * SS * sizeof(float), stream);
    fused_score<<<dim3(KC, bc, 2), 256, 0, stream>>>(
        Ahi + off, Alo + off, Phi + off, Plo + off,
        G1h, G1l, G2h, G2l, v1, v2, scoreBuf, bc);
    softmax_attn<<<dim3(bc * 2, 8), 256, 0, stream>>>(scoreBuf, attnW);
    pv_res2<<<dim3(bc * 2, 8), 256, 0, stream>>>(
        attnW, PTh + off, ATh + off, A + off, P + off,
        out1 + off, out2 + off, bc);
  }
}

// Round 9
// 243.627 us; speedup vs baseline: 1.0753x; 1.0753x over previous
//
#include <hip/hip_runtime.h>

// Problem constants: B=32, S=128, H=512, K=8
#define BB 32
#define SS 128
#define HH 512
#define KC 8
#define NN 4096  // KC*HH

typedef __attribute__((ext_vector_type(8))) short bf16x8;
typedef __attribute__((ext_vector_type(4))) float f32x4;

__device__ __forceinline__ unsigned short f2bf(float f) {
  unsigned int u = __float_as_uint(f);
  u += 0x7fffu + ((u >> 16) & 1u);   // round-to-nearest-even
  return (unsigned short)(u >> 16);
}
__device__ __forceinline__ float bf2f(unsigned short h) {
  return __uint_as_float(((unsigned int)h) << 16);
}
__device__ __forceinline__ float tanh_fast(float x) {
  float e = __expf(2.0f * x);
  return 1.0f - 2.0f / (e + 1.0f);
}
__device__ __forceinline__ void async16(const void* g, void* lds) {
  __builtin_amdgcn_global_load_lds(
      (const __attribute__((address_space(1))) unsigned int*)g,
      (__attribute__((address_space(3))) unsigned int*)lds, 16, 0, 0);
}

// ---- conversion kernels ---------------------------------------------------
// A/P: fp32 [B,S,H] -> hi/lo row-major AND hi-only transposed [B,H,S], one read.
__global__ __launch_bounds__(256) void convert_ap(
    const float* __restrict__ Xa, const float* __restrict__ Xb,
    unsigned short* __restrict__ hia, unsigned short* __restrict__ loa,
    unsigned short* __restrict__ hiTa,
    unsigned short* __restrict__ hib, unsigned short* __restrict__ lob,
    unsigned short* __restrict__ hiTb) {
  const float* X = blockIdx.z ? Xb : Xa;
  unsigned short* hi = blockIdx.z ? hib : hia;
  unsigned short* lo = blockIdx.z ? lob : loa;
  unsigned short* hiT = blockIdx.z ? hiTb : hiTa;
  __shared__ float t[32][33];
  const int h0 = blockIdx.x * 32;
  const int s0 = (blockIdx.y & 3) * 32;
  const size_t b = blockIdx.y >> 2;
  const int tx = threadIdx.x & 31, ty = threadIdx.x >> 5;
#pragma unroll
  for (int r = 0; r < 4; ++r) {
    float f = X[b * (SS * HH) + (size_t)(s0 + ty + r * 8) * HH + h0 + tx];
    t[ty + r * 8][tx] = f;
    size_t o = b * (SS * HH) + (size_t)(s0 + ty + r * 8) * HH + h0 + tx;
    unsigned short h = f2bf(f);
    hi[o] = h;
    lo[o] = f2bf(f - bf2f(h));
  }
  __syncthreads();
#pragma unroll
  for (int r = 0; r < 4; ++r) {
    float f = t[tx][ty + r * 8];
    size_t o = b * (SS * HH) + (size_t)(h0 + ty + r * 8) * SS + s0 + tx;
    hiT[o] = f2bf(f);
  }
}

// G [512, 4096] fp32 -> G^T [4096, 512] (hi, lo) bf16; z selects G1/G2.
__global__ __launch_bounds__(256) void convert_transpose_g(
    const float* __restrict__ Ga, const float* __restrict__ Gb,
    unsigned short* __restrict__ ha, unsigned short* __restrict__ la,
    unsigned short* __restrict__ hb, unsigned short* __restrict__ lb) {
  const float* G = blockIdx.z ? Gb : Ga;
  unsigned short* hiT = blockIdx.z ? hb : ha;
  unsigned short* loT = blockIdx.z ? lb : la;
  __shared__ float t[32][33];
  const int bx = blockIdx.x * 32;  // n
  const int by = blockIdx.y * 32;  // k
  const int tx = threadIdx.x & 31, ty = threadIdx.x >> 5;
#pragma unroll
  for (int r = 0; r < 4; ++r)
    t[ty + r * 8][tx] = G[(size_t)(by + ty + r * 8) * NN + bx + tx];
  __syncthreads();
#pragma unroll
  for (int r = 0; r < 4; ++r) {
    float f = t[tx][ty + r * 8];
    size_t o = (size_t)(bx + ty + r * 8) * HH + by + tx;
    unsigned short h = f2bf(f);
    hiT[o] = h;
    loT[o] = f2bf(f - bf2f(h));
  }
}

// ---- fused proj+score: block (k, b, br) -----------------------------------
// Phase A (per g-chunk gc of 128): proj subtile [128 s x 128 g] for fixed k.
// Phase B (per 32-g slice): proj frags -> LDS bf16 hi/lo; R slice staged;
// raw[s,t] += proj . R (3-product split).
// Epilogue: PLAIN stores scoreBuf[br,b,k][s][t] = v[k]*tanh(raw) — no atomics.
__global__ __launch_bounds__(256, 2) void fused_score(
    const unsigned short* __restrict__ Ahi, const unsigned short* __restrict__ Alo,
    const unsigned short* __restrict__ Phi, const unsigned short* __restrict__ Plo,
    const unsigned short* __restrict__ G1h, const unsigned short* __restrict__ G1l,
    const unsigned short* __restrict__ G2h, const unsigned short* __restrict__ G2l,
    const float* __restrict__ v1, const float* __restrict__ v2,
    float* __restrict__ scoreBuf, int bc) {
  __shared__ char smem[32768];
  unsigned short* sm = (unsigned short*)smem;
  const int k = blockIdx.x;   // fast dim: id mod 8 == k -> one k per XCD (G L2-resident)
  const int b = blockIdx.y;
  const int brx = blockIdx.z;
  const int tid = threadIdx.x, w = tid >> 6, L = tid & 63;
  const int wm = w >> 1, wn = w & 1;
  const int q = L >> 4, c = L & 15;

  // Left operand: aspect A for BOTH branches (faithful to source).
  const unsigned short* Ah = Ahi + (size_t)b * SS * HH;
  const unsigned short* Al = Alo + (size_t)b * SS * HH;
  const unsigned short* Gh = brx ? G2h : G1h;
  const unsigned short* Gl = brx ? G2l : G1l;
  // Right matrix: branch0 -> polarity, branch1 -> aspect.
  const unsigned short* Rh = (brx ? Ahi : Phi) + (size_t)b * SS * HH;
  const unsigned short* Rl = (brx ? Alo : Plo) + (size_t)b * SS * HH;

  const int srow = w * 32 + (L >> 2);
  const int scol = (L & 3) * 8;
  const unsigned short* pAh = Ah + (size_t)srow * HH + scol;
  const unsigned short* pAl = Al + (size_t)srow * HH + scol;
  const unsigned short* pRh = Rh + (size_t)srow * HH + scol;
  const unsigned short* pRl = Rl + (size_t)srow * HH + scol;
  const unsigned lbase = (unsigned)w * 2048;
  const int ar = (wm * 64 + (L & 15)) * 32 + (L >> 4) * 8;
  const int br_ = (wn * 64 + (L & 15)) * 32 + (L >> 4) * 8;

  f32x4 raw[4][4];
#pragma unroll
  for (int i = 0; i < 4; ++i)
#pragma unroll
    for (int j = 0; j < 4; ++j) raw[i][j] = (f32x4)(0.0f);

  for (int gc = 0; gc < 4; ++gc) {
    // ---------- phase A: proj subtile ----------
    const size_t n0 = (size_t)k * 512 + (size_t)gc * 128;
    const unsigned short* pBh = Gh + (n0 + srow) * HH + scol;
    const unsigned short* pBl = Gl + (n0 + srow) * HH + scol;
    f32x4 acc[4][4];
#pragma unroll
    for (int i = 0; i < 4; ++i)
#pragma unroll
      for (int j = 0; j < 4; ++j) acc[i][j] = (f32x4)(0.0f);

    for (int kt = 0; kt < 16; ++kt) {
      const int k0 = kt * 32;
      async16(pAh + k0, smem + lbase);
      async16(pAh + k0 + 16 * HH, smem + lbase + 1024);
      async16(pAl + k0, smem + 8192 + lbase);
      async16(pAl + k0 + 16 * HH, smem + 8192 + lbase + 1024);
      async16(pBh + k0, smem + 16384 + lbase);
      async16(pBh + k0 + 16 * HH, smem + 16384 + lbase + 1024);
      async16(pBl + k0, smem + 24576 + lbase);
      async16(pBl + k0 + 16 * HH, smem + 24576 + lbase + 1024);
      __syncthreads();
      bf16x8 ah[4], al[4], bh[4], bl[4];
#pragma unroll
      for (int i = 0; i < 4; ++i) {
        ah[i] = *(const bf16x8*)&sm[ar + i * 512];
        al[i] = *(const bf16x8*)&sm[4096 + ar + i * 512];
        bh[i] = *(const bf16x8*)&sm[8192 + br_ + i * 512];
        bl[i] = *(const bf16x8*)&sm[12288 + br_ + i * 512];
      }
#pragma unroll
      for (int i = 0; i < 4; ++i)
#pragma unroll
        for (int j = 0; j < 4; ++j) {
          acc[i][j] = __builtin_amdgcn_mfma_f32_16x16x32_bf16(ah[i], bh[j], acc[i][j], 0, 0, 0);
          acc[i][j] = __builtin_amdgcn_mfma_f32_16x16x32_bf16(ah[i], bl[j], acc[i][j], 0, 0, 0);
          acc[i][j] = __builtin_amdgcn_mfma_f32_16x16x32_bf16(al[i], bh[j], acc[i][j], 0, 0, 0);
        }
      __syncthreads();
    }

    // ---------- phase B: raw += projTile @ R, in 32-g slices ----------
#pragma unroll
    for (int sl = 0; sl < 4; ++sl) {
      const int gg = gc * 128 + sl * 32;
      async16(pRh + gg, smem + 16384 + lbase);
      async16(pRh + gg + 16 * HH, smem + 16384 + lbase + 1024);
      async16(pRl + gg, smem + 24576 + lbase);
      async16(pRl + gg + 16 * HH, smem + 24576 + lbase + 1024);
      if (wn == (sl >> 1)) {
        const int jj0 = (sl & 1) * 2;
#pragma unroll
        for (int i = 0; i < 4; ++i)
#pragma unroll
          for (int jd = 0; jd < 2; ++jd) {
            f32x4 vfr = acc[i][jj0 + jd];
            const int gl = jd * 16 + c;
#pragma unroll
            for (int r = 0; r < 4; ++r) {
              const int row = wm * 64 + i * 16 + q * 4 + r;
              float f = vfr[r];
              unsigned short h = f2bf(f);
              sm[row * 32 + gl] = h;
              sm[4096 + row * 32 + gl] = f2bf(f - bf2f(h));
            }
          }
      }
      __syncthreads();
      bf16x8 sa_h[4], sa_l[4], sb_h[4], sb_l[4];
#pragma unroll
      for (int i = 0; i < 4; ++i) {
        const int ao = (wm * 64 + i * 16 + (L & 15)) * 32 + (L >> 4) * 8;
        sa_h[i] = *(const bf16x8*)&sm[ao];
        sa_l[i] = *(const bf16x8*)&sm[4096 + ao];
      }
#pragma unroll
      for (int j = 0; j < 4; ++j) {
        const int bo = (wn * 64 + j * 16 + (L & 15)) * 32 + (L >> 4) * 8;
        sb_h[j] = *(const bf16x8*)&sm[8192 + bo];
        sb_l[j] = *(const bf16x8*)&sm[12288 + bo];
      }
#pragma unroll
      for (int i = 0; i < 4; ++i)
#pragma unroll
        for (int j = 0; j < 4; ++j) {
          raw[i][j] = __builtin_amdgcn_mfma_f32_16x16x32_bf16(sa_h[i], sb_h[j], raw[i][j], 0, 0, 0);
          raw[i][j] = __builtin_amdgcn_mfma_f32_16x16x32_bf16(sa_h[i], sb_l[j], raw[i][j], 0, 0, 0);
          raw[i][j] = __builtin_amdgcn_mfma_f32_16x16x32_bf16(sa_l[i], sb_h[j], raw[i][j], 0, 0, 0);
        }
      __syncthreads();
    }
  }

  // ---------- epilogue: plain stores to this block's own k-slice ----------
  const float vk = (brx ? v2 : v1)[k];
  float* dst = scoreBuf + (((size_t)brx * bc + b) * KC + k) * (SS * SS);
#pragma unroll
  for (int i = 0; i < 4; ++i)
#pragma unroll
    for (int j = 0; j < 4; ++j) {
      const int row0 = wm * 64 + i * 16 + q * 4;
      const int col = wn * 64 + j * 16 + c;
#pragma unroll
      for (int r = 0; r < 4; ++r)
        dst[(size_t)(row0 + r) * SS + col] = vk * tanh_fast(raw[i][j][r]);
    }
}

// ---- k-sum + softmax over t -> attn weights bf16-hi -----------------------
// grid (groups = bc*2, 8 rt); block = 16 s-rows x 128 t.
__global__ __launch_bounds__(256) void softmax_attn(
    const float* __restrict__ scoreBuf, unsigned short* __restrict__ attnW) {
  const int x = blockIdx.x, rt = blockIdx.y;
  const int tid = threadIdx.x, tx = tid & 15, ty = tid >> 4;
  const size_t rowoff = (size_t)(rt * 16 + ty) * SS + tx * 8;
  const float* src = scoreBuf + (size_t)x * KC * (SS * SS) + rowoff;
  float sc[8];
#pragma unroll
  for (int j = 0; j < 8; ++j) sc[j] = 0.0f;
#pragma unroll
  for (int k = 0; k < KC; ++k) {
    float4 a0 = *(const float4*)&src[(size_t)k * (SS * SS)];
    float4 a1 = *(const float4*)&src[(size_t)k * (SS * SS) + 4];
    sc[0] += a0.x; sc[1] += a0.y; sc[2] += a0.z; sc[3] += a0.w;
    sc[4] += a1.x; sc[5] += a1.y; sc[6] += a1.z; sc[7] += a1.w;
  }
  float mx = sc[0];
#pragma unroll
  for (int j = 1; j < 8; ++j) mx = fmaxf(mx, sc[j]);
#pragma unroll
  for (int off = 1; off < 16; off <<= 1) mx = fmaxf(mx, __shfl_xor(mx, off, 16));
  float p[8], ssum = 0.0f;
#pragma unroll
  for (int j = 0; j < 8; ++j) { p[j] = __expf(sc[j] - mx); ssum += p[j]; }
#pragma unroll
  for (int off = 1; off < 16; off <<= 1) ssum += __shfl_xor(ssum, off, 16);
  float inv = 1.0f / ssum;
  ushort4 h0, h1;
  h0.x = f2bf(p[0] * inv); h0.y = f2bf(p[1] * inv);
  h0.z = f2bf(p[2] * inv); h0.w = f2bf(p[3] * inv);
  h1.x = f2bf(p[4] * inv); h1.y = f2bf(p[5] * inv);
  h1.z = f2bf(p[6] * inv); h1.w = f2bf(p[7] * inv);
  size_t abase = (size_t)x * (SS * SS) + rowoff;
  *(ushort4*)&attnW[abase] = h0;
  *(ushort4*)&attnW[abase + 4] = h1;
}

// ---- PV + residual: out[64 s x 128 h] = base + attn[64x128] @ V[128x128] --
__global__ __launch_bounds__(256) void pv_res2(
    const unsigned short* __restrict__ attnW,
    const unsigned short* __restrict__ PTh, const unsigned short* __restrict__ ATh,
    const float* __restrict__ Abase, const float* __restrict__ Pbase,
    float* __restrict__ out1, float* __restrict__ out2, int bc) {
  __shared__ char smem[12288];  // A [64][32] 4 KB | B [128][32] 8 KB
  unsigned short* sm = (unsigned short*)smem;
  const int x = blockIdx.x;
  const int brx = (x >= bc) ? 1 : 0;
  const int b = x - (brx ? bc : 0);
  const int hc = blockIdx.y & 3, sh = blockIdx.y >> 2;
  const int tid = threadIdx.x, w = tid >> 6, L = tid & 63;
  const int wm = w >> 1, wn = w & 1;

  const unsigned short* Aw = attnW + (size_t)x * (SS * SS) + (size_t)(sh * 64) * SS;
  const unsigned short* Vh = (brx ? ATh : PTh) + (size_t)b * HH * SS + (size_t)(hc * 128) * SS;
  const float* base = (brx ? Pbase : Abase) + (size_t)b * SS * HH;
  float* outp = (brx ? out2 : out1) + (size_t)b * SS * HH;

  f32x4 acc[2][4];
#pragma unroll
  for (int i = 0; i < 2; ++i)
#pragma unroll
    for (int j = 0; j < 4; ++j) acc[i][j] = (f32x4)(0.0f);

  const int arow = w * 16 + (L >> 2);
  const int brow = w * 32 + (L >> 2);
  const int scol = (L & 3) * 8;
  const int afr = (wm * 32 + (L & 15)) * 32 + (L >> 4) * 8;
  const int bfr = 2048 + (wn * 64 + (L & 15)) * 32 + (L >> 4) * 8;

  for (int kt = 0; kt < 4; ++kt) {
    const int k0 = kt * 32;
    async16(Aw + (size_t)arow * SS + k0 + scol, smem + w * 1024);
    async16(Vh + (size_t)brow * SS + k0 + scol, smem + 4096 + w * 2048);
    async16(Vh + (size_t)(brow + 16) * SS + k0 + scol, smem + 4096 + w * 2048 + 1024);
    __syncthreads();
    bf16x8 af[2], bf[4];
#pragma unroll
    for (int i = 0; i < 2; ++i) af[i] = *(const bf16x8*)&sm[afr + i * 512];
#pragma unroll
    for (int j = 0; j < 4; ++j) bf[j] = *(const bf16x8*)&sm[bfr + j * 512];
#pragma unroll
    for (int i = 0; i < 2; ++i)
#pragma unroll
      for (int j = 0; j < 4; ++j)
        acc[i][j] = __builtin_amdgcn_mfma_f32_16x16x32_bf16(af[i], bf[j], acc[i][j], 0, 0, 0);
    __syncthreads();
  }

  const int q = L >> 4, c = L & 15;
#pragma unroll
  for (int i = 0; i < 2; ++i)
#pragma unroll
    for (int j = 0; j < 4; ++j) {
      const int srow = sh * 64 + wm * 32 + i * 16 + q * 4;
      const int hcol = hc * 128 + wn * 64 + j * 16 + c;
#pragma unroll
      for (int r = 0; r < 4; ++r) {
        size_t o = (size_t)(srow + r) * HH + hcol;
        outp[o] = base[o] + acc[i][j][r];
      }
    }
}

extern "C" void kernel_launch(void* const* d_in, const int* in_sizes, int n_in,
                              void* d_out, int out_size, void* d_ws, size_t ws_size,
                              hipStream_t stream) {
  const float* A  = (const float*)d_in[0];
  const float* P  = (const float*)d_in[1];
  const float* G1 = (const float*)d_in[2];
  const float* G2 = (const float*)d_in[3];
  const float* v1 = (const float*)d_in[4];
  const float* v2 = (const float*)d_in[5];
  float* out1 = (float*)d_out;
  float* out2 = out1 + (size_t)BB * SS * HH;

  const size_t NA = (size_t)BB * SS * HH;  // 2M
  const size_t NG = (size_t)HH * KC * HH;  // 2M
  unsigned short* Ahi = (unsigned short*)d_ws;
  unsigned short* Alo = Ahi + NA;
  unsigned short* Phi = Alo + NA;
  unsigned short* Plo = Phi + NA;
  unsigned short* G1h = Plo + NA;
  unsigned short* G1l = G1h + NG;
  unsigned short* G2h = G1l + NG;
  unsigned short* G2l = G2h + NG;
  unsigned short* ATh = G2l + NG;
  unsigned short* PTh = ATh + NA;

  const size_t fixedBytes = (6 * NA + 4 * NG) * sizeof(unsigned short);  // 40 MB
  // per batch: scoreBuf 2*KC*16K fp32 (1 MB) + attnW 2*16K bf16 (64 KB)
  const size_t perB = 2 * (size_t)SS * SS * (KC * sizeof(float) + sizeof(unsigned short));
  size_t rem = ws_size > fixedBytes ? ws_size - fixedBytes : 0;
  int Bc = (int)(rem / perB);
  if (Bc < 1) Bc = 1;
  if (Bc > BB) Bc = BB;
  float* scoreBuf = (float*)((char*)d_ws + fixedBytes);
  unsigned short* attnW = (unsigned short*)(scoreBuf + 2 * (size_t)Bc * KC * SS * SS);

  convert_ap<<<dim3(HH / 32, (SS / 32) * BB, 2), 256, 0, stream>>>(
      A, P, Ahi, Alo, ATh, Phi, Plo, PTh);
  convert_transpose_g<<<dim3(NN / 32, HH / 32, 2), 256, 0, stream>>>(
      G1, G2, G1h, G1l, G2h, G2l);

  for (int b0 = 0; b0 < BB; b0 += Bc) {
    int bc = (Bc < BB - b0) ? Bc : (BB - b0);
    size_t off = (size_t)b0 * SS * HH;  // element offset (both layouts)
    fused_score<<<dim3(KC, bc, 2), 256, 0, stream>>>(
        Ahi + off, Alo + off, Phi + off, Plo + off,
        G1h, G1l, G2h, G2l, v1, v2, scoreBuf, bc);
    softmax_attn<<<dim3(bc * 2, 8), 256, 0, stream>>>(scoreBuf, attnW);
    pv_res2<<<dim3(bc * 2, 8), 256, 0, stream>>>(
        attnW, PTh + off, ATh + off, A + off, P + off,
        out1 + off, out2 + off, bc);
  }
}